// Round 3
// baseline (430.041 us; speedup 1.0000x reference)
//
#include <hip/hip_runtime.h>

typedef unsigned short u16;
typedef __attribute__((ext_vector_type(8))) __bf16 bf16x8;
typedef __attribute__((ext_vector_type(4))) float floatx4;

#define DDIM 2048
#define MROWS 16384   // 4*4096
#define BK 64

__device__ __forceinline__ u16 f2bf(float f) {
    unsigned int u = __builtin_bit_cast(unsigned int, f);
    u = (u + 0x7fffu + ((u >> 16) & 1u)) >> 16;   // RNE
    return (u16)u;
}

__device__ __forceinline__ float wave_sum(float v) {
#pragma unroll
    for (int o = 32; o > 0; o >>= 1) v += __shfl_down(v, o, 64);
    return v;
}
__device__ __forceinline__ float wave_max(float v) {
#pragma unroll
    for (int o = 32; o > 0; o >>= 1) v = fmaxf(v, __shfl_down(v, o, 64));
    return v;
}

// ---------------- partial sums of |W| ----------------
__global__ __launch_bounds__(256) void absmean_part(const float4* __restrict__ W4,
                                                    float* __restrict__ partial) {
    float s = 0.f;
    for (int i = blockIdx.x * 256 + threadIdx.x; i < (DDIM * DDIM / 4); i += 1024 * 256) {
        float4 v = W4[i];
        s += fabsf(v.x) + fabsf(v.y) + fabsf(v.z) + fabsf(v.w);
    }
    s = wave_sum(s);
    __shared__ float red[4];
    if ((threadIdx.x & 63) == 0) red[threadIdx.x >> 6] = s;
    __syncthreads();
    if (threadIdx.x == 0) partial[blockIdx.x] = red[0] + red[1] + red[2] + red[3];
}

// ---------------- transpose (optionally fused w_scale finalize + ternary quantize) ----
template <bool QUANT>
__global__ __launch_bounds__(256) void transpose_k(const float* __restrict__ in,
                                                   float* __restrict__ out,
                                                   const float* __restrict__ partial) {
    __shared__ float tile[64][65];
    const int t = threadIdx.x;
    float wsc = 0.f, half_t = 0.f;
    if (QUANT) {
        __shared__ float wred[4];
        float s = partial[t] + partial[t + 256] + partial[t + 512] + partial[t + 768];
        s = wave_sum(s);
        if ((t & 63) == 0) wred[t >> 6] = s;
        __syncthreads();
        float m = (wred[0] + wred[1] + wred[2] + wred[3]) * (1.0f / (float)(DDIM * DDIM));
        wsc = fmaxf(m, 1e-6f);
        half_t = 0.5f * wsc;
        __syncthreads();
    }
    const int tx = t & 63;
    const int ty = t >> 6;
    const int r0 = blockIdx.y * 64;
    const int c0 = blockIdx.x * 64;
#pragma unroll
    for (int i = 0; i < 16; ++i) {
        int r = ty + i * 4;
        float w = in[(size_t)(r0 + r) * DDIM + c0 + tx];
        if (QUANT) w = (w > half_t ? wsc : 0.f) + (w < -half_t ? -wsc : 0.f);
        tile[r][tx] = w;
    }
    __syncthreads();
#pragma unroll
    for (int i = 0; i < 16; ++i) {
        int r = ty + i * 4;
        out[(size_t)(c0 + r) * DDIM + r0 + tx] = tile[tx][r];
    }
}

// ---------------- row FWHT (length 2048) -------------------------------------
// Coalesced: thread t holds elements [4t..4t+3] (v0..v3) and [1024+4t..] (v4..v7).
// v-index bits: bit0=elem bit0, bit1=elem bit1, bit2=elem bit10.
// Remaining: elem bits 2..7 = lane bits (shfl_xor), elem bits 8..9 = thread bits 6..7 (LDS).
// Per-bit butterflies commute, so stage order is free.
template <bool BF16OUT>
__global__ __launch_bounds__(256) void fwht_rows(const float* __restrict__ in,
                                                 void* __restrict__ out) {
    __shared__ float s0[DDIM];
    __shared__ float s1[DDIM];
    const int row = blockIdx.x;
    const int t = threadIdx.x;
    const int lane = t & 63;
    const float4* rp = (const float4*)(in + (size_t)row * DDIM);
    float4 a = rp[t], b = rp[t + 256];
    float v[8] = {a.x, a.y, a.z, a.w, b.x, b.y, b.z, b.w};

    // elem bits 0,1,10 — in registers
#pragma unroll
    for (int h = 1; h <= 4; h <<= 1)
#pragma unroll
        for (int j = 0; j < 8; ++j)
            if (!(j & h)) { float x = v[j], y = v[j | h]; v[j] = x + y; v[j | h] = x - y; }

    // elem bits 2..7 — lane bits 0..5 via shfl_xor
#pragma unroll
    for (int m = 1; m <= 32; m <<= 1)
#pragma unroll
        for (int j = 0; j < 8; ++j) {
            float p = __shfl_xor(v[j], m, 64);
            v[j] = (lane & m) ? (p - v[j]) : (p + v[j]);
        }

    // elem bit 8 — thread bit 6, via LDS buffer 0
    ((float4*)s0)[2 * t] = make_float4(v[0], v[1], v[2], v[3]);
    ((float4*)s0)[2 * t + 1] = make_float4(v[4], v[5], v[6], v[7]);
    __syncthreads();
    {
        int p1 = t ^ 64;
        float4 pa = ((const float4*)s0)[2 * p1], pb = ((const float4*)s0)[2 * p1 + 1];
        float pv[8] = {pa.x, pa.y, pa.z, pa.w, pb.x, pb.y, pb.z, pb.w};
#pragma unroll
        for (int j = 0; j < 8; ++j) v[j] = (t & 64) ? (pv[j] - v[j]) : (pv[j] + v[j]);
    }
    // elem bit 9 — thread bit 7, via LDS buffer 1
    ((float4*)s1)[2 * t] = make_float4(v[0], v[1], v[2], v[3]);
    ((float4*)s1)[2 * t + 1] = make_float4(v[4], v[5], v[6], v[7]);
    __syncthreads();
    {
        int p2 = t ^ 128;
        float4 pa = ((const float4*)s1)[2 * p2], pb = ((const float4*)s1)[2 * p2 + 1];
        float pv[8] = {pa.x, pa.y, pa.z, pa.w, pb.x, pb.y, pb.z, pb.w};
#pragma unroll
        for (int j = 0; j < 8; ++j) v[j] = (t & 128) ? (pv[j] - v[j]) : (pv[j] + v[j]);
    }

    if (BF16OUT) {
        u16* op = (u16*)out + (size_t)row * DDIM;
        uint2 o0, o1;
        o0.x = (unsigned)f2bf(v[0]) | ((unsigned)f2bf(v[1]) << 16);
        o0.y = (unsigned)f2bf(v[2]) | ((unsigned)f2bf(v[3]) << 16);
        o1.x = (unsigned)f2bf(v[4]) | ((unsigned)f2bf(v[5]) << 16);
        o1.y = (unsigned)f2bf(v[6]) | ((unsigned)f2bf(v[7]) << 16);
        ((uint2*)op)[t] = o0;
        ((uint2*)op)[t + 256] = o1;
    } else {
        float* op = (float*)out + (size_t)row * DDIM;
        ((float4*)op)[t] = make_float4(v[0], v[1], v[2], v[3]);
        ((float4*)op)[t + 256] = make_float4(v[4], v[5], v[6], v[7]);
    }
}

// ---------------- fused LayerNorm + int4 fake-quant -> bf16 ----------------
// Coalesced: thread t holds elements [4t..4t+3] and [1024+4t..1024+4t+3].
__global__ __launch_bounds__(256) void ln_quant(const float* __restrict__ X,
                                                const float* __restrict__ G,
                                                const float* __restrict__ Bt,
                                                u16* __restrict__ XQ) {
    const int row = blockIdx.x;
    const int t = threadIdx.x;
    const float4* rp = (const float4*)(X + (size_t)row * DDIM);
    float4 v0 = rp[t], v1 = rp[t + 256];
    float v[8] = {v0.x, v0.y, v0.z, v0.w, v1.x, v1.y, v1.z, v1.w};

    __shared__ float redA[4], redB[4], redC[4];
    const int wv = t >> 6, ln = t & 63;

    float s = 0.f, s2 = 0.f;
#pragma unroll
    for (int j = 0; j < 8; ++j) { s += v[j]; s2 += v[j] * v[j]; }
#pragma unroll
    for (int o = 32; o > 0; o >>= 1) {
        s += __shfl_down(s, o, 64);
        s2 += __shfl_down(s2, o, 64);
    }
    if (ln == 0) { redA[wv] = s; redB[wv] = s2; }
    __syncthreads();
    const float mu = (redA[0] + redA[1] + redA[2] + redA[3]) * (1.f / (float)DDIM);
    const float ex2 = (redB[0] + redB[1] + redB[2] + redB[3]) * (1.f / (float)DDIM);
    const float var = ex2 - mu * mu;
    const float rstd = rsqrtf(var + 1e-5f);

    const float4* gp = (const float4*)G;
    const float4* bp = (const float4*)Bt;
    float4 g0 = gp[t], g1 = gp[t + 256];
    float4 b0 = bp[t], b1 = bp[t + 256];
    float gg[8] = {g0.x, g0.y, g0.z, g0.w, g1.x, g1.y, g1.z, g1.w};
    float bb[8] = {b0.x, b0.y, b0.z, b0.w, b1.x, b1.y, b1.z, b1.w};

    float y[8];
    float am = 0.f;
#pragma unroll
    for (int j = 0; j < 8; ++j) {
        y[j] = (v[j] - mu) * rstd * gg[j] + bb[j];
        am = fmaxf(am, fabsf(y[j]));
    }
    float w = wave_max(am);
    if (ln == 0) redC[wv] = w;
    __syncthreads();
    const float scale = fmaxf(fmaxf(fmaxf(redC[0], redC[1]), fmaxf(redC[2], redC[3])), 1e-6f);

    const float r7 = 7.f / scale, s7 = scale / 7.f;
    unsigned int q[4];
#pragma unroll
    for (int j = 0; j < 8; j += 2) {
        float qa = fminf(fmaxf(rintf(y[j] * r7), -7.f), 7.f);
        float qb = fminf(fmaxf(rintf(y[j + 1] * r7), -7.f), 7.f);
        q[j >> 1] = (unsigned)f2bf(qa * s7) | ((unsigned)f2bf(qb * s7) << 16);
    }
    uint2 o0, o1;
    o0.x = q[0]; o0.y = q[1]; o1.x = q[2]; o1.y = q[3];
    uint2* orow = (uint2*)(XQ + (size_t)row * DDIM);
    orow[t] = o0;
    orow[t + 256] = o1;
}

// ---------------- GEMM: C[16384][2048] = A[16384][2048] * B[2048(N)][2048(K)]^T --------
// BK=64, XOR-swizzled 16B chunk placement: LDS row r position p holds global
// chunk p^(r&7); fragment reads hit 2 lanes/bank-quad => conflict-free b128.
// XCD-aware block swizzle: p&7 = XCD; each XCD gets a contiguous 16-m-band slab
// so its resident A working set (~2-3MB) fits the 4MB per-XCD L2.
__device__ __forceinline__ void gl_lds16(const u16* g, u16* l) {
    __builtin_amdgcn_global_load_lds((const __attribute__((address_space(1))) void*)g,
                                     (__attribute__((address_space(3))) void*)l,
                                     16, 0, 0);
}

__global__ __launch_bounds__(256) void gemm_bt(const u16* __restrict__ A,
                                               const u16* __restrict__ B,
                                               float* __restrict__ C) {
    __shared__ __align__(16) u16 As[128 * BK];
    __shared__ __align__(16) u16 Bs[128 * BK];
    const int p = blockIdx.y * 16 + blockIdx.x;   // 0..2047
    const int bn = (p >> 3) & 15;
    const int bm = (p & 7) * 16 + (p >> 7);
    const int t = threadIdx.x;
    const int wave = t >> 6, lane = t & 63;
    const int m_off = (wave >> 1) << 6;
    const int n_off = (wave & 1) << 6;
    const int lr = lane & 15, kq = lane >> 4;

    floatx4 acc[4][4];
#pragma unroll
    for (int i = 0; i < 4; ++i)
#pragma unroll
        for (int j = 0; j < 4; ++j) acc[i][j] = {0.f, 0.f, 0.f, 0.f};

    // staging: slot = i*256+t; row = i*32 + (t>>3); pos = t&7; global chunk = pos^(row&7)
    const int srow = t >> 3;                         // 0..31, (row&7)==(srow&7) for all i
    const int sc = ((t & 7) ^ (srow & 7)) << 3;      // element offset of global chunk
    const u16* Ag = A + (size_t)(bm * 128 + srow) * DDIM + sc;
    const u16* Bg = B + (size_t)(bn * 128 + srow) * DDIM + sc;
    u16* Asl = As + t * 8;
    u16* Bsl = Bs + t * 8;

    for (int kt = 0; kt < DDIM / BK; ++kt) {
        const size_t ko = (size_t)kt * BK;
#pragma unroll
        for (int i = 0; i < 4; ++i) {
            gl_lds16(Ag + (size_t)(i * 32) * DDIM + ko, Asl + i * 2048);
            gl_lds16(Bg + (size_t)(i * 32) * DDIM + ko, Bsl + i * 2048);
        }
        __syncthreads();

#pragma unroll
        for (int s = 0; s < 2; ++s) {
            const int swz = ((kq + 4 * s) ^ (lr & 7)) << 3;
            bf16x8 af[4], bfr[4];
#pragma unroll
            for (int mi = 0; mi < 4; ++mi)
                af[mi] = *(const bf16x8*)(As + (m_off + mi * 16 + lr) * BK + swz);
#pragma unroll
            for (int ni = 0; ni < 4; ++ni)
                bfr[ni] = *(const bf16x8*)(Bs + (n_off + ni * 16 + lr) * BK + swz);
#pragma unroll
            for (int mi = 0; mi < 4; ++mi)
#pragma unroll
                for (int ni = 0; ni < 4; ++ni)
                    acc[mi][ni] = __builtin_amdgcn_mfma_f32_16x16x32_bf16(af[mi], bfr[ni],
                                                                          acc[mi][ni], 0, 0, 0);
        }
        __syncthreads();
    }

    const int mrow = kq * 4;
    float* Cb = C + (size_t)(bm * 128 + m_off) * DDIM + bn * 128 + n_off;
#pragma unroll
    for (int mi = 0; mi < 4; ++mi)
#pragma unroll
        for (int ni = 0; ni < 4; ++ni)
#pragma unroll
            for (int r = 0; r < 4; ++r)
                Cb[(size_t)(mi * 16 + mrow + r) * DDIM + ni * 16 + lr] = acc[mi][ni][r];
}

extern "C" void kernel_launch(void* const* d_in, const int* in_sizes, int n_in,
                              void* d_out, int out_size, void* d_ws, size_t ws_size,
                              hipStream_t stream) {
    const float* X  = (const float*)d_in[0];  // (4,4096,2048)
    const float* W  = (const float*)d_in[1];  // (2048,2048)
    const float* G  = (const float*)d_in[2];  // gamma
    const float* Bt = (const float*)d_in[3];  // beta
    float* out = (float*)d_out;

    char* ws = (char*)d_ws;
    u16*   xq   = (u16*)ws;                                       // 67,108,864 B
    float* bufA = (float*)(ws + (size_t)67108864);                // 16,777,216 B
    float* bufB = (float*)(ws + (size_t)67108864 + 16777216);     // 16,777,216 B
    float* partial = bufB;        // 1024 floats, transient (consumed by transpose<true>)
    u16*   w3      = (u16*)bufB;  // final bf16 weights, reuses bufB

    // w_scale partials
    absmean_part<<<1024, 256, 0, stream>>>((const float4*)W, partial);
    // w3 = H * ternary(W) * H, laid out [N=o][K=d] in bf16:
    transpose_k<true><<<dim3(32, 32), 256, 0, stream>>>(W, bufA, partial);     // bufA[d][o] = t^T
    fwht_rows<false><<<2048, 256, 0, stream>>>(bufA, (void*)bufB);             // bufB[d][o] = (H t)^T
    transpose_k<false><<<dim3(32, 32), 256, 0, stream>>>(bufB, bufA, nullptr); // bufA[o][d] = H t
    fwht_rows<true><<<2048, 256, 0, stream>>>(bufA, (void*)w3);                // w3[o][d] = H t H (bf16)
    // activations
    ln_quant<<<MROWS, 256, 0, stream>>>(X, G, Bt, xq);
    // GEMM
    gemm_bt<<<dim3(16, 128), 256, 0, stream>>>(xq, w3, out);
}

// Round 4
// 418.618 us; speedup vs baseline: 1.0273x; 1.0273x over previous
//
#include <hip/hip_runtime.h>

typedef unsigned short u16;
typedef __attribute__((ext_vector_type(8))) __bf16 bf16x8;
typedef __attribute__((ext_vector_type(16))) float floatx16;

#define DDIM 2048
#define MROWS 16384   // 4*4096
#define BK 64

__device__ __forceinline__ u16 f2bf(float f) {
    unsigned int u = __builtin_bit_cast(unsigned int, f);
    u = (u + 0x7fffu + ((u >> 16) & 1u)) >> 16;   // RNE
    return (u16)u;
}

__device__ __forceinline__ float wave_sum(float v) {
#pragma unroll
    for (int o = 32; o > 0; o >>= 1) v += __shfl_down(v, o, 64);
    return v;
}
__device__ __forceinline__ float wave_max(float v) {
#pragma unroll
    for (int o = 32; o > 0; o >>= 1) v = fmaxf(v, __shfl_down(v, o, 64));
    return v;
}

// ---------------- partial sums of |W| ----------------
__global__ __launch_bounds__(256) void absmean_part(const float4* __restrict__ W4,
                                                    float* __restrict__ partial) {
    float s = 0.f;
    for (int i = blockIdx.x * 256 + threadIdx.x; i < (DDIM * DDIM / 4); i += 1024 * 256) {
        float4 v = W4[i];
        s += fabsf(v.x) + fabsf(v.y) + fabsf(v.z) + fabsf(v.w);
    }
    s = wave_sum(s);
    __shared__ float red[4];
    if ((threadIdx.x & 63) == 0) red[threadIdx.x >> 6] = s;
    __syncthreads();
    if (threadIdx.x == 0) partial[blockIdx.x] = red[0] + red[1] + red[2] + red[3];
}

// ---------------- transpose (optionally fused w_scale finalize + ternary quantize) ----
template <bool QUANT>
__global__ __launch_bounds__(256) void transpose_k(const float* __restrict__ in,
                                                   float* __restrict__ out,
                                                   const float* __restrict__ partial) {
    __shared__ float tile[64][65];
    const int t = threadIdx.x;
    float wsc = 0.f, half_t = 0.f;
    if (QUANT) {
        __shared__ float wred[4];
        float s = partial[t] + partial[t + 256] + partial[t + 512] + partial[t + 768];
        s = wave_sum(s);
        if ((t & 63) == 0) wred[t >> 6] = s;
        __syncthreads();
        float m = (wred[0] + wred[1] + wred[2] + wred[3]) * (1.0f / (float)(DDIM * DDIM));
        wsc = fmaxf(m, 1e-6f);
        half_t = 0.5f * wsc;
        __syncthreads();
    }
    const int tx = t & 63;
    const int ty = t >> 6;
    const int r0 = blockIdx.y * 64;
    const int c0 = blockIdx.x * 64;
#pragma unroll
    for (int i = 0; i < 16; ++i) {
        int r = ty + i * 4;
        float w = in[(size_t)(r0 + r) * DDIM + c0 + tx];
        if (QUANT) w = (w > half_t ? wsc : 0.f) + (w < -half_t ? -wsc : 0.f);
        tile[r][tx] = w;
    }
    __syncthreads();
#pragma unroll
    for (int i = 0; i < 16; ++i) {
        int r = ty + i * 4;
        out[(size_t)(c0 + r) * DDIM + r0 + tx] = tile[tx][r];
    }
}

// ---------------- row FWHT (length 2048) -------------------------------------
// Coalesced: thread t holds elements [4t..4t+3] (v0..v3) and [1024+4t..] (v4..v7).
// v-index bits: bit0=elem bit0, bit1=elem bit1, bit2=elem bit10.
// Remaining: elem bits 2..7 = lane bits (shfl_xor), elem bits 8..9 = thread bits 6..7 (LDS).
// Per-bit butterflies commute, so stage order is free.
template <bool BF16OUT>
__global__ __launch_bounds__(256) void fwht_rows(const float* __restrict__ in,
                                                 void* __restrict__ out) {
    __shared__ float s0[DDIM];
    __shared__ float s1[DDIM];
    const int row = blockIdx.x;
    const int t = threadIdx.x;
    const int lane = t & 63;
    const float4* rp = (const float4*)(in + (size_t)row * DDIM);
    float4 a = rp[t], b = rp[t + 256];
    float v[8] = {a.x, a.y, a.z, a.w, b.x, b.y, b.z, b.w};

    // elem bits 0,1,10 — in registers
#pragma unroll
    for (int h = 1; h <= 4; h <<= 1)
#pragma unroll
        for (int j = 0; j < 8; ++j)
            if (!(j & h)) { float x = v[j], y = v[j | h]; v[j] = x + y; v[j | h] = x - y; }

    // elem bits 2..7 — lane bits 0..5 via shfl_xor
#pragma unroll
    for (int m = 1; m <= 32; m <<= 1)
#pragma unroll
        for (int j = 0; j < 8; ++j) {
            float p = __shfl_xor(v[j], m, 64);
            v[j] = (lane & m) ? (p - v[j]) : (p + v[j]);
        }

    // elem bit 8 — thread bit 6, via LDS buffer 0
    ((float4*)s0)[2 * t] = make_float4(v[0], v[1], v[2], v[3]);
    ((float4*)s0)[2 * t + 1] = make_float4(v[4], v[5], v[6], v[7]);
    __syncthreads();
    {
        int p1 = t ^ 64;
        float4 pa = ((const float4*)s0)[2 * p1], pb = ((const float4*)s0)[2 * p1 + 1];
        float pv[8] = {pa.x, pa.y, pa.z, pa.w, pb.x, pb.y, pb.z, pb.w};
#pragma unroll
        for (int j = 0; j < 8; ++j) v[j] = (t & 64) ? (pv[j] - v[j]) : (pv[j] + v[j]);
    }
    // elem bit 9 — thread bit 7, via LDS buffer 1
    ((float4*)s1)[2 * t] = make_float4(v[0], v[1], v[2], v[3]);
    ((float4*)s1)[2 * t + 1] = make_float4(v[4], v[5], v[6], v[7]);
    __syncthreads();
    {
        int p2 = t ^ 128;
        float4 pa = ((const float4*)s1)[2 * p2], pb = ((const float4*)s1)[2 * p2 + 1];
        float pv[8] = {pa.x, pa.y, pa.z, pa.w, pb.x, pb.y, pb.z, pb.w};
#pragma unroll
        for (int j = 0; j < 8; ++j) v[j] = (t & 128) ? (pv[j] - v[j]) : (pv[j] + v[j]);
    }

    if (BF16OUT) {
        u16* op = (u16*)out + (size_t)row * DDIM;
        uint2 o0, o1;
        o0.x = (unsigned)f2bf(v[0]) | ((unsigned)f2bf(v[1]) << 16);
        o0.y = (unsigned)f2bf(v[2]) | ((unsigned)f2bf(v[3]) << 16);
        o1.x = (unsigned)f2bf(v[4]) | ((unsigned)f2bf(v[5]) << 16);
        o1.y = (unsigned)f2bf(v[6]) | ((unsigned)f2bf(v[7]) << 16);
        ((uint2*)op)[t] = o0;
        ((uint2*)op)[t + 256] = o1;
    } else {
        float* op = (float*)out + (size_t)row * DDIM;
        ((float4*)op)[t] = make_float4(v[0], v[1], v[2], v[3]);
        ((float4*)op)[t + 256] = make_float4(v[4], v[5], v[6], v[7]);
    }
}

// ---------------- fused LayerNorm + int4 fake-quant -> bf16 ----------------
// Coalesced: thread t holds elements [4t..4t+3] and [1024+4t..1024+4t+3].
__global__ __launch_bounds__(256) void ln_quant(const float* __restrict__ X,
                                                const float* __restrict__ G,
                                                const float* __restrict__ Bt,
                                                u16* __restrict__ XQ) {
    const int row = blockIdx.x;
    const int t = threadIdx.x;
    const float4* rp = (const float4*)(X + (size_t)row * DDIM);
    float4 v0 = rp[t], v1 = rp[t + 256];
    float v[8] = {v0.x, v0.y, v0.z, v0.w, v1.x, v1.y, v1.z, v1.w};

    __shared__ float redA[4], redB[4], redC[4];
    const int wv = t >> 6, ln = t & 63;

    float s = 0.f, s2 = 0.f;
#pragma unroll
    for (int j = 0; j < 8; ++j) { s += v[j]; s2 += v[j] * v[j]; }
#pragma unroll
    for (int o = 32; o > 0; o >>= 1) {
        s += __shfl_down(s, o, 64);
        s2 += __shfl_down(s2, o, 64);
    }
    if (ln == 0) { redA[wv] = s; redB[wv] = s2; }
    __syncthreads();
    const float mu = (redA[0] + redA[1] + redA[2] + redA[3]) * (1.f / (float)DDIM);
    const float ex2 = (redB[0] + redB[1] + redB[2] + redB[3]) * (1.f / (float)DDIM);
    const float var = ex2 - mu * mu;
    const float rstd = rsqrtf(var + 1e-5f);

    const float4* gp = (const float4*)G;
    const float4* bp = (const float4*)Bt;
    float4 g0 = gp[t], g1 = gp[t + 256];
    float4 b0 = bp[t], b1 = bp[t + 256];
    float gg[8] = {g0.x, g0.y, g0.z, g0.w, g1.x, g1.y, g1.z, g1.w};
    float bb[8] = {b0.x, b0.y, b0.z, b0.w, b1.x, b1.y, b1.z, b1.w};

    float y[8];
    float am = 0.f;
#pragma unroll
    for (int j = 0; j < 8; ++j) {
        y[j] = (v[j] - mu) * rstd * gg[j] + bb[j];
        am = fmaxf(am, fabsf(y[j]));
    }
    float w = wave_max(am);
    if (ln == 0) redC[wv] = w;
    __syncthreads();
    const float scale = fmaxf(fmaxf(fmaxf(redC[0], redC[1]), fmaxf(redC[2], redC[3])), 1e-6f);

    const float r7 = 7.f / scale, s7 = scale / 7.f;
    unsigned int q[4];
#pragma unroll
    for (int j = 0; j < 8; j += 2) {
        float qa = fminf(fmaxf(rintf(y[j] * r7), -7.f), 7.f);
        float qb = fminf(fmaxf(rintf(y[j + 1] * r7), -7.f), 7.f);
        q[j >> 1] = (unsigned)f2bf(qa * s7) | ((unsigned)f2bf(qb * s7) << 16);
    }
    uint2 o0, o1;
    o0.x = q[0]; o0.y = q[1]; o1.x = q[2]; o1.y = q[3];
    uint2* orow = (uint2*)(XQ + (size_t)row * DDIM);
    orow[t] = o0;
    orow[t + 256] = o1;
}

// ---------------- GEMM: C[16384][2048] = A[16384][2048] * B[2048(N)][2048(K)]^T --------
// 32x32x16 MFMA (15% higher ceiling than 16x16x32, half the instruction count).
// BK=64, XOR-swizzled 16B chunk placement: LDS row r position p holds global
// chunk p^(r&7); fragment reads spread 8 lanes/bank-quad = b128 minimum.
// Plain dispatch order (R3's XCD swizzle regressed: traffic down, latency up).
__device__ __forceinline__ void gl_lds16(const u16* g, u16* l) {
    __builtin_amdgcn_global_load_lds((const __attribute__((address_space(1))) void*)g,
                                     (__attribute__((address_space(3))) void*)l,
                                     16, 0, 0);
}

__global__ __launch_bounds__(256) void gemm_bt(const u16* __restrict__ A,
                                               const u16* __restrict__ B,
                                               float* __restrict__ C) {
    __shared__ __align__(16) u16 As[128 * BK];
    __shared__ __align__(16) u16 Bs[128 * BK];
    const int bm = blockIdx.y, bn = blockIdx.x;
    const int t = threadIdx.x;
    const int wave = t >> 6, lane = t & 63;
    const int m_off = (wave >> 1) << 6;
    const int n_off = (wave & 1) << 6;
    const int l31 = lane & 31, lh = lane >> 5;

    floatx16 acc[2][2];
#pragma unroll
    for (int mi = 0; mi < 2; ++mi)
#pragma unroll
        for (int ni = 0; ni < 2; ++ni)
#pragma unroll
            for (int e = 0; e < 16; ++e) acc[mi][ni][e] = 0.f;

    // staging: slot = i*256+t; row = i*32 + (t>>3); pos = t&7; global chunk = pos^(row&7)
    const int srow = t >> 3;                         // 0..31, (row&7)==(srow&7) for all i
    const int sc = ((t & 7) ^ (srow & 7)) << 3;      // element offset of global chunk
    const u16* Ag = A + (size_t)(bm * 128 + srow) * DDIM + sc;
    const u16* Bg = B + (size_t)(bn * 128 + srow) * DDIM + sc;
    u16* Asl = As + t * 8;
    u16* Bsl = Bs + t * 8;

    for (int kt = 0; kt < DDIM / BK; ++kt) {
        const size_t ko = (size_t)kt * BK;
#pragma unroll
        for (int i = 0; i < 4; ++i) {
            gl_lds16(Ag + (size_t)(i * 32) * DDIM + ko, Asl + i * 2048);
            gl_lds16(Bg + (size_t)(i * 32) * DDIM + ko, Bsl + i * 2048);
        }
        __syncthreads();

#pragma unroll
        for (int ks = 0; ks < 4; ++ks) {
            // fragment: [mn = l31][k = ks*16 + lh*8 + j] -> 16B chunk (ks*2+lh)^(l31&7)
            const int swz = ((ks * 2 + lh) ^ (l31 & 7)) << 3;
            bf16x8 af[2], bfr[2];
#pragma unroll
            for (int mi = 0; mi < 2; ++mi)
                af[mi] = *(const bf16x8*)(As + (m_off + mi * 32 + l31) * BK + swz);
#pragma unroll
            for (int ni = 0; ni < 2; ++ni)
                bfr[ni] = *(const bf16x8*)(Bs + (n_off + ni * 32 + l31) * BK + swz);
#pragma unroll
            for (int mi = 0; mi < 2; ++mi)
#pragma unroll
                for (int ni = 0; ni < 2; ++ni)
                    acc[mi][ni] = __builtin_amdgcn_mfma_f32_32x32x16_bf16(af[mi], bfr[ni],
                                                                          acc[mi][ni], 0, 0, 0);
        }
        __syncthreads();
    }

    // C/D layout (measured m74/m101): col = lane&31, row = (reg&3) + 8*(reg>>2) + 4*(lane>>5)
    float* Cb = C + (size_t)(bm * 128 + m_off) * DDIM + bn * 128 + n_off;
#pragma unroll
    for (int mi = 0; mi < 2; ++mi)
#pragma unroll
        for (int ni = 0; ni < 2; ++ni)
#pragma unroll
            for (int r = 0; r < 16; ++r) {
                const int rl = (r & 3) + 8 * (r >> 2) + 4 * lh;
                Cb[(size_t)(mi * 32 + rl) * DDIM + ni * 32 + l31] = acc[mi][ni][r];
            }
}

extern "C" void kernel_launch(void* const* d_in, const int* in_sizes, int n_in,
                              void* d_out, int out_size, void* d_ws, size_t ws_size,
                              hipStream_t stream) {
    const float* X  = (const float*)d_in[0];  // (4,4096,2048)
    const float* W  = (const float*)d_in[1];  // (2048,2048)
    const float* G  = (const float*)d_in[2];  // gamma
    const float* Bt = (const float*)d_in[3];  // beta
    float* out = (float*)d_out;

    char* ws = (char*)d_ws;
    u16*   xq   = (u16*)ws;                                       // 67,108,864 B
    float* bufA = (float*)(ws + (size_t)67108864);                // 16,777,216 B
    float* bufB = (float*)(ws + (size_t)67108864 + 16777216);     // 16,777,216 B
    float* partial = bufB;        // 1024 floats, transient (consumed by transpose<true>)
    u16*   w3      = (u16*)bufB;  // final bf16 weights, reuses bufB

    // w_scale partials
    absmean_part<<<1024, 256, 0, stream>>>((const float4*)W, partial);
    // w3 = H * ternary(W) * H, laid out [N=o][K=d] in bf16:
    transpose_k<true><<<dim3(32, 32), 256, 0, stream>>>(W, bufA, partial);     // bufA[d][o] = t^T
    fwht_rows<false><<<2048, 256, 0, stream>>>(bufA, (void*)bufB);             // bufB[d][o] = (H t)^T
    transpose_k<false><<<dim3(32, 32), 256, 0, stream>>>(bufB, bufA, nullptr); // bufA[o][d] = H t
    fwht_rows<true><<<2048, 256, 0, stream>>>(bufA, (void*)w3);                // w3[o][d] = H t H (bf16)
    // activations
    ln_quant<<<MROWS, 256, 0, stream>>>(X, G, Bt, xq);
    // GEMM
    gemm_bt<<<dim3(16, 128), 256, 0, stream>>>(xq, w3, out);
}